// Round 1
// baseline (12.300 us; speedup 1.0000x reference)
//
#include <hip/hip_runtime.h>

// ResBlock_88510686036612
//
// Reference:  r1 = adder2d(x, W1); r1 = relu(r1); r2 = adder2d(r1, W2);
//             out = r2 * 0.1 + x
//
// Key identity (holds for ALL inputs, exact program transformation):
//   adder2d(...) = -sum(|...|) <= 0 everywhere  =>  relu(adder2d(x,W1)) == 0.
//   Then adder2d(0, W2)[b,o,h,w] = -sum_{c,kh,kw} |0 - W2[o,c,kh,kw]|
//                                = -||W2[o]||_1   (constant per channel o,
//                                  padding contributes |0 - w| identically).
//   => out[b,o,h,w] = x[b,o,h,w] - 0.1 * ||W2[o]||_1
//
// Kernel 1: 64 per-channel L1 norms of W2 (576 elems each) -> d_ws (scaled by 0.1)
// Kernel 2: out = x - l1[channel]  (float4-vectorized, HBM-bound)

#define CKK 576  // C*K*K = 64*3*3

__global__ void w2_l1_kernel(const float* __restrict__ w2,
                             float* __restrict__ l1) {
    const int o = blockIdx.x;    // 64 blocks, one output channel each
    const int t = threadIdx.x;   // 64 threads = 1 wave
    const float* wp = w2 + o * CKK;
    float s = 0.0f;
#pragma unroll
    for (int i = 0; i < CKK / 64; ++i)   // 9 coalesced strided loads
        s += fabsf(wp[t + 64 * i]);
    // full-wave butterfly reduce (wave = 64 lanes on gfx950)
#pragma unroll
    for (int off = 32; off > 0; off >>= 1)
        s += __shfl_down(s, off, 64);
    if (t == 0) l1[o] = 0.1f * s;        // fold RES_SCALE here
}

__global__ void resblock_out_kernel(const float4* __restrict__ x4,
                                    const float* __restrict__ l1,
                                    float4* __restrict__ out4,
                                    int n4) {
    const int idx = blockIdx.x * blockDim.x + threadIdx.x;
    if (idx >= n4) return;
    // x layout [B,C,H,W] = [8,64,64,64]; 1024 float4 per (b,c) plane
    const int c = (idx >> 10) & 63;
    const float s = l1[c];               // uniform-ish broadcast, L2-resident
    float4 v = x4[idx];
    v.x -= s; v.y -= s; v.z -= s; v.w -= s;
    out4[idx] = v;
}

extern "C" void kernel_launch(void* const* d_in, const int* in_sizes, int n_in,
                              void* d_out, int out_size, void* d_ws, size_t ws_size,
                              hipStream_t stream) {
    const float* x  = (const float*)d_in[0];   // [8,64,64,64]
    // d_in[1] = W1 — provably unused (relu(adder2d(x,W1)) == 0 identically)
    const float* w2 = (const float*)d_in[2];   // [64,64,3,3]
    float* out = (float*)d_out;
    float* l1  = (float*)d_ws;                 // 64 floats of scratch

    w2_l1_kernel<<<64, 64, 0, stream>>>(w2, l1);

    const int n4 = out_size / 4;               // 524288 float4
    const int block = 256;
    const int grid = (n4 + block - 1) / block; // 2048 blocks
    resblock_out_kernel<<<grid, block, 0, stream>>>(
        (const float4*)x, l1, (float4*)out, n4);
}

// Round 2
// 10.139 us; speedup vs baseline: 1.2131x; 1.2131x over previous
//
#include <hip/hip_runtime.h>

// ResBlock_88510686036612 — single fused kernel.
//
// Identity (exact, input-independent):
//   adder2d = -sum|.| <= 0  =>  relu(adder2d(x,W1)) == 0
//   => out[b,o,h,w] = x[b,o,h,w] - 0.1 * ||W2[o]||_1
//
// One block per (b,c) plane (4096 floats). Each wave redundantly computes
// the channel's L1 norm of W2 in-register (W2 is 147KB -> L2-resident), then
// all threads do the broadcast-subtract over the plane. No LDS, no barrier,
// single launch.

__global__ __launch_bounds__(256) void resblock_fused_kernel(
    const float4* __restrict__ x4,
    const float*  __restrict__ w2,
    float4*       __restrict__ out4) {
    const int t    = threadIdx.x;
    const int lane = t & 63;
    const int c    = blockIdx.x & 63;   // [B,C,H,W]: plane index % C = channel

    // ---- issue the plane's x loads first (independent of norm chain) ----
    const int base = (blockIdx.x << 10) + t;   // 1024 float4 per plane
    float4 v0 = x4[base];
    float4 v1 = x4[base + 256];
    float4 v2 = x4[base + 512];
    float4 v3 = x4[base + 768];

    // ---- per-wave L1 norm of W2[c] : 576 floats = 144 float4 ----
    const float4* wp = (const float4*)(w2 + c * 576);
    float4 a = wp[lane];
    float4 b = wp[lane + 64];
    float s = fabsf(a.x) + fabsf(a.y) + fabsf(a.z) + fabsf(a.w)
            + fabsf(b.x) + fabsf(b.y) + fabsf(b.z) + fabsf(b.w);
    if (lane < 16) {
        float4 d = wp[lane + 128];
        s += fabsf(d.x) + fabsf(d.y) + fabsf(d.z) + fabsf(d.w);
    }
#pragma unroll
    for (int off = 32; off; off >>= 1)      // 64-lane butterfly
        s += __shfl_xor(s, off, 64);
    s *= 0.1f;                               // fold RES_SCALE

    // ---- out = x - s ----
    v0.x -= s; v0.y -= s; v0.z -= s; v0.w -= s;
    v1.x -= s; v1.y -= s; v1.z -= s; v1.w -= s;
    v2.x -= s; v2.y -= s; v2.z -= s; v2.w -= s;
    v3.x -= s; v3.y -= s; v3.z -= s; v3.w -= s;
    out4[base]       = v0;
    out4[base + 256] = v1;
    out4[base + 512] = v2;
    out4[base + 768] = v3;
}

extern "C" void kernel_launch(void* const* d_in, const int* in_sizes, int n_in,
                              void* d_out, int out_size, void* d_ws, size_t ws_size,
                              hipStream_t stream) {
    const float* x  = (const float*)d_in[0];   // [8,64,64,64]
    // d_in[1] = W1 — provably unused (relu(adder2d(x,W1)) == 0 identically)
    const float* w2 = (const float*)d_in[2];   // [64,64,3,3]
    float* out = (float*)d_out;

    const int planes = out_size / 4096;        // 8*64 = 512 blocks
    resblock_fused_kernel<<<planes, 256, 0, stream>>>(
        (const float4*)x, w2, (float4*)out);
}

// Round 4
// 10.006 us; speedup vs baseline: 1.2293x; 1.0133x over previous
//
#include <hip/hip_runtime.h>

// ResBlock_88510686036612 — single fused kernel, occupancy-tuned.
//
// Identity (exact, input-independent):
//   adder2d = -sum|.| <= 0  =>  relu(adder2d(x,W1)) == 0
//   => out[b,o,h,w] = x[b,o,h,w] - 0.1 * ||W2[o]||_1
//
// 2048 blocks x 256 threads, one float4 per thread (8 blocks/CU for latency
// hiding). Each wave redundantly computes its channel's L1 norm of W2
// in-register (W2 = 147KB, L2-resident; redundant reads are L2 traffic only).
// No LDS, no barriers. Nontemporal stores for the write-once output.

typedef float vfloat4 __attribute__((ext_vector_type(4)));  // native vec for nt-store

__global__ __launch_bounds__(256) void resblock_fused_kernel(
    const vfloat4* __restrict__ x4,
    const float*   __restrict__ w2,
    vfloat4*       __restrict__ out4) {
    const int t    = threadIdx.x;
    const int lane = t & 63;

    // 1024 float4 per (b,c) plane; 256 float4 per block -> 4 blocks/plane
    const int idx = (blockIdx.x << 8) + t;
    const int c   = (idx >> 10) & 63;          // channel of this float4

    // ---- issue the x load first (independent of the norm chain) ----
    vfloat4 v = x4[idx];

    // ---- per-wave L1 norm of W2[c] : 576 floats = 144 float4 (L2-hit) ----
    const vfloat4* wp = (const vfloat4*)(w2 + c * 576);
    vfloat4 a = wp[lane];
    vfloat4 b = wp[lane + 64];
    float s = fabsf(a.x) + fabsf(a.y) + fabsf(a.z) + fabsf(a.w)
            + fabsf(b.x) + fabsf(b.y) + fabsf(b.z) + fabsf(b.w);
    if (lane < 16) {
        vfloat4 d = wp[lane + 128];
        s += fabsf(d.x) + fabsf(d.y) + fabsf(d.z) + fabsf(d.w);
    }
#pragma unroll
    for (int off = 32; off; off >>= 1)          // 64-lane butterfly
        s += __shfl_xor(s, off, 64);
    s *= 0.1f;                                  // fold RES_SCALE

    // ---- out = x - s (streaming store, bypass L2 retention) ----
    v -= s;
    __builtin_nontemporal_store(v, &out4[idx]);
}

extern "C" void kernel_launch(void* const* d_in, const int* in_sizes, int n_in,
                              void* d_out, int out_size, void* d_ws, size_t ws_size,
                              hipStream_t stream) {
    const float* x  = (const float*)d_in[0];   // [8,64,64,64]
    // d_in[1] = W1 — provably unused (relu(adder2d(x,W1)) == 0 identically)
    const float* w2 = (const float*)d_in[2];   // [64,64,3,3]
    float* out = (float*)d_out;

    const int n4   = out_size / 4;             // 524288 float4
    const int grid = n4 / 256;                 // 2048 blocks
    resblock_fused_kernel<<<grid, 256, 0, stream>>>(
        (const vfloat4*)x, w2, (vfloat4*)out);
}